// Round 1
// baseline (51.197 us; speedup 1.0000x reference)
//
#include <hip/hip_runtime.h>
#include <math.h>
#include <stdint.h>

#define GSEG 4096
#define BLK 256
#define ITEMS 8

typedef unsigned long long u64;

// order-preserving float->uint encoding (monotone for all non-NaN floats)
__device__ __forceinline__ unsigned fkey(float f){
  unsigned u = __float_as_uint(f);
  return (u & 0x80000000u) ? ~u : (u | 0x80000000u);
}
__device__ __forceinline__ float fdec(unsigned k){
  unsigned u = (k & 0x80000000u) ? (k & 0x7FFFFFFFu) : ~k;
  return __uint_as_float(u);
}
__device__ __forceinline__ float dot16(const float* __restrict__ hr,
                                       const float* __restrict__ w, float b){
  float s = 0.f;
#pragma unroll
  for (int k = 0; k < 16; ++k) s = fmaf(hr[k], w[k], s);
  return s + b;
}
__device__ __forceinline__ u64 shflxor64(u64 v, int off){
  unsigned lo = (unsigned)v, hi = (unsigned)(v >> 32);
  lo = __shfl_xor(lo, off); hi = __shfl_xor(hi, off);
  return ((u64)hi << 32) | lo;
}

__global__ void k_init(unsigned* M, float* S, float* E, u64* P){
  int g = blockIdx.x * blockDim.x + threadIdx.x;
  if (g < GSEG){ M[g] = fkey(-INFINITY); S[g] = 0.f; E[g] = 0.f; P[g] = 0ull; }
}

// K1: x_i = h_i . Wn + bn for valid nodes; store x; segment max into M (encoded)
__global__ void k1_max(const float* __restrict__ h, const int* __restrict__ bidx,
                       const float* __restrict__ Wn, const float* __restrict__ bn,
                       float* __restrict__ X, unsigned* __restrict__ M,
                       int N, int usex){
  const int lane = threadIdx.x & 63;
  const long base = (long)blockIdx.x * (BLK * ITEMS);
  float wreg[16];
#pragma unroll
  for (int k = 0; k < 16; ++k) wreg[k] = Wn[k];
  const float bb = bn[0];
  for (int it = 0; it < ITEMS; ++it){
    long i = base + it * BLK + threadIdx.x;
    bool valid = false; int g = 0; float x = 0.f;
    if (i < N){
      g = bidx[i];
      valid = ((unsigned)g < (unsigned)GSEG);   // negatives (overflowed) dropped
      if (valid){
        x = dot16(h + i * 16, wreg, bb);
        if (usex) X[i] = x;
      }
    }
    u64 todo = __ballot(valid);
    while (todo){
      int lead = __ffsll(todo) - 1;
      int g0 = __shfl(g, lead);
      bool mine = valid && (g == g0);
      u64 mm = __ballot(mine);
      float v = mine ? x : -INFINITY;
#pragma unroll
      for (int off = 32; off; off >>= 1) v = fmaxf(v, __shfl_xor(v, off));
      if (lane == lead) atomicMax(&M[g0], fkey(v));
      todo &= ~mm;
    }
  }
}

// K2: S_g = sum exp(x - m_g)
__global__ void k2_sum(const float* __restrict__ h, const float* __restrict__ Wn,
                       const float* __restrict__ bn,
                       const float* __restrict__ X, const int* __restrict__ bidx,
                       const unsigned* __restrict__ M, float* __restrict__ S,
                       int N, int usex){
  const int lane = threadIdx.x & 63;
  const long base = (long)blockIdx.x * (BLK * ITEMS);
  for (int it = 0; it < ITEMS; ++it){
    long i = base + it * BLK + threadIdx.x;
    bool valid = false; int g = 0; float e = 0.f;
    if (i < N){
      g = bidx[i];
      valid = ((unsigned)g < (unsigned)GSEG);
      if (valid){
        float x = usex ? X[i] : dot16(h + i * 16, Wn, bn[0]);
        e = expf(x - fdec(M[g]));
      }
    }
    u64 todo = __ballot(valid);
    while (todo){
      int lead = __ffsll(todo) - 1;
      int g0 = __shfl(g, lead);
      bool mine = valid && (g == g0);
      u64 mm = __ballot(mine);
      float v = mine ? e : 0.f;
#pragma unroll
      for (int off = 32; off; off >>= 1) v += __shfl_xor(v, off);
      if (lane == lead) atomicAdd(&S[g0], v);
      todo &= ~mm;
    }
  }
}

// K3: pert = ((x-m)-logS)+gumbel; packed argmax (ties -> larger idx);
//     E_g = sum exp(lp)*lp  (node entropy numerator, ref-faithful)
__global__ void k3_pert(const float* __restrict__ h, const float* __restrict__ Wn,
                        const float* __restrict__ bn,
                        const float* __restrict__ X, const int* __restrict__ bidx,
                        const float* __restrict__ gn,
                        const unsigned* __restrict__ M, const float* __restrict__ S,
                        float* __restrict__ E, u64* __restrict__ P,
                        int N, int usex){
  const int lane = threadIdx.x & 63;
  const long base = (long)blockIdx.x * (BLK * ITEMS);
  for (int it = 0; it < ITEMS; ++it){
    long i = base + it * BLK + threadIdx.x;
    bool valid = false; int g = 0; float ee = 0.f; u64 pk = 0ull;
    if (i < N){
      g = bidx[i];
      valid = ((unsigned)g < (unsigned)GSEG);
      if (valid){
        float x = usex ? X[i] : dot16(h + i * 16, Wn, bn[0]);
        float m = fdec(M[g]);
        float logs = logf(S[g]);
        float sh = x - m;
        float lp = sh - logs;
        float pert = lp + gn[i];
        pk = ((u64)fkey(pert) << 32) | (unsigned)i;
        ee = expf(lp) * lp;
      }
    }
    u64 todo = __ballot(valid);
    while (todo){
      int lead = __ffsll(todo) - 1;
      int g0 = __shfl(g, lead);
      bool mine = valid && (g == g0);
      u64 mm = __ballot(mine);
      float v = mine ? ee : 0.f;
      u64 q = mine ? pk : 0ull;
#pragma unroll
      for (int off = 32; off; off >>= 1){
        v += __shfl_xor(v, off);
        u64 t = shflxor64(q, off);
        q = (t > q) ? t : q;
      }
      if (lane == lead){ atomicAdd(&E[g0], v); atomicMax(&P[g0], q); }
      todo &= ~mm;
    }
  }
}

// K4: one wave per graph. Empty segment (S==0): chosen=INT32_MIN, row clamps to 0,
// node_ent = -0.0, node_lp = logp[0]. Action head + log_softmax + gumbel argmax.
__global__ void k4_final(const float* __restrict__ h, const float* __restrict__ Wn,
                         const float* __restrict__ bn,
                         const float* __restrict__ Wa, const float* __restrict__ ba,
                         const float* __restrict__ ga,
                         const unsigned* __restrict__ M, const float* __restrict__ S,
                         const float* __restrict__ E, const u64* __restrict__ P,
                         float* __restrict__ out){
  const int g = blockIdx.x;
  const int lane = threadIdx.x;   // 64 threads = 1 wave; lanes 32..63 duplicate
  const int j = lane & 31;
  float Sg = S[g];
  bool empty = (Sg == 0.f);
  long row; float chosen_f, node_lp, node_ent;
  if (empty){
    row = 0;                                  // jax gather clamps INT32_MIN -> 0
    chosen_f = -2147483648.0f;                // INT32_MIN as float32 (exact)
    float x0 = dot16(h, Wn, bn[0]);
    node_lp = (x0 - fdec(M[0])) - logf(S[0]); // node 0 belongs to graph 0
    node_ent = 0.f;                           // -segment_sum(empty) = -0.0
  } else {
    int ci = (int)(unsigned)(P[g] & 0xFFFFFFFFull);
    row = ci;
    chosen_f = (float)ci;                     // < 2^24, exact in f32
    float xc = dot16(h + row * 16, Wn, bn[0]);
    node_lp = (xc - fdec(M[g])) - logf(Sg);
    node_ent = -E[g];
  }
  const float* hr = h + row * 16;
  float lg = ba[j];
#pragma unroll
  for (int k = 0; k < 16; ++k) lg = fmaf(hr[k], Wa[k * 32 + j], lg);
  float am = lg;
#pragma unroll
  for (int off = 16; off; off >>= 1) am = fmaxf(am, __shfl_xor(am, off));
  float sh = lg - am;
  float ex = expf(sh);
  float sum = ex;
#pragma unroll
  for (int off = 16; off; off >>= 1) sum += __shfl_xor(sum, off);
  float al = sh - logf(sum);
  float pa = al + ga[g * 32 + j];
  // jnp.argmax: FIRST index on ties -> maximize (key, 31-j)
  u64 pk = ((u64)fkey(pa) << 32) | (unsigned)(31 - j);
#pragma unroll
  for (int off = 16; off; off >>= 1){ u64 t = shflxor64(pk, off); pk = (t > pk) ? t : pk; }
  int act = 31 - (int)(unsigned)(pk & 0xFFFFFFFFull);
  float a_lp = __shfl(al, act);
  float pe = expf(al) * al;
#pragma unroll
  for (int off = 16; off; off >>= 1) pe += __shfl_xor(pe, off);
  float a_ent = -pe;
  if (lane == 0){
    out[2 * g]     = chosen_f;
    out[2 * g + 1] = (float)act;
    out[2 * GSEG + g] = node_lp + a_lp;     // logprob
    out[3 * GSEG + g] = node_ent + a_ent;   // entropy
  }
}

extern "C" void kernel_launch(void* const* d_in, const int* in_sizes, int n_in,
                              void* d_out, int out_size, void* d_ws, size_t ws_size,
                              hipStream_t stream){
  const float* h  = (const float*)d_in[0];
  const int* bidx = (const int*)d_in[1];
  const float* Wn = (const float*)d_in[2];
  const float* bn = (const float*)d_in[3];
  const float* Wa = (const float*)d_in[4];
  const float* ba = (const float*)d_in[5];
  const float* gn = (const float*)d_in[6];
  const float* ga = (const float*)d_in[7];
  const int N = in_sizes[1];
  float* out = (float*)d_out;

  char* w = (char*)d_ws;
  unsigned* M = (unsigned*)w;              // 4096 u32
  float* S    = (float*)(w + 16384);       // 4096 f32
  float* E    = (float*)(w + 32768);       // 4096 f32
  u64*   P    = (u64*)(w + 49152);         // 4096 u64 (8B aligned)
  float* X    = (float*)(w + 81920);       // N f32 node logits
  int usex = (ws_size >= (size_t)81920 + (size_t)N * sizeof(float)) ? 1 : 0;

  hipLaunchKernelGGL(k_init, dim3((GSEG + 255) / 256), dim3(256), 0, stream, M, S, E, P);
  int nb = (N + BLK * ITEMS - 1) / (BLK * ITEMS);
  hipLaunchKernelGGL(k1_max,  dim3(nb), dim3(BLK), 0, stream, h, bidx, Wn, bn, X, M, N, usex);
  hipLaunchKernelGGL(k2_sum,  dim3(nb), dim3(BLK), 0, stream, h, Wn, bn, X, bidx, M, S, N, usex);
  hipLaunchKernelGGL(k3_pert, dim3(nb), dim3(BLK), 0, stream, h, Wn, bn, X, bidx, gn, M, S, E, P, N, usex);
  hipLaunchKernelGGL(k4_final, dim3(GSEG), dim3(64), 0, stream, h, Wn, bn, Wa, ba, ga, M, S, E, P, out);
}